// Round 3
// baseline (826.112 us; speedup 1.0000x reference)
//
#include <hip/hip_runtime.h>
#include <cstdint>
#include <cstddef>

// Problem dims (fixed)
#define T_TOKENS 8192
#define H_DIM    1024
#define F_DIM    4096
#define E_NUM    8

typedef __bf16 bf16x8 __attribute__((ext_vector_type(8)));
typedef float  f32x4  __attribute__((ext_vector_type(4)));
typedef unsigned short ushort8 __attribute__((ext_vector_type(8)));

#define AS_GLOBAL(p) ((const __attribute__((address_space(1))) void*)(p))
#define AS_LDS(p)    ((__attribute__((address_space(3))) void*)(p))

__device__ inline unsigned short f2b(float f) {
  unsigned int u = __float_as_uint(f);
  unsigned int r = (u + 0x7fffu + ((u >> 16) & 1u)) >> 16;   // RNE
  return (unsigned short)r;
}
__device__ inline float b2f(unsigned short u) {
  return __uint_as_float(((unsigned int)u) << 16);
}
// gelu(v) = 0.5 v (1 + tanh(u)) = v * sigmoid(2u), u = 0.79788456(v + 0.044715 v^3)
__device__ inline float gelu_fast(float v) {
  float u2 = 1.5957691216057308f * v * (1.0f + 0.044715f * v * v);
  return v / (1.0f + __expf(-u2));
}

// ---------------------------------------------------------------------------
// Transpose + fp32->bf16 cast:  in [E][R][C] fp32  ->  out [E][C][R] bf16
// Also zeroes the 24-word routing meta block when zc != nullptr.
// ---------------------------------------------------------------------------
__global__ __launch_bounds__(256) void transpose_cast_kernel(
    const float* __restrict__ in, unsigned short* __restrict__ out, int R, int C,
    int* __restrict__ zc)
{
  __shared__ float tile[64][65];
  const int tid = threadIdx.x;
  if (zc && blockIdx.x == 0 && blockIdx.y == 0 && blockIdx.z == 0 && tid < 24)
    zc[tid] = 0;
  const int e  = blockIdx.z;
  const int c0 = blockIdx.x * 64;
  const int r0 = blockIdx.y * 64;
  const float* src = in + (size_t)e * R * C;
  unsigned short* dst = out + (size_t)e * R * C;
  const int rl  = tid >> 4;
  const int cl4 = (tid & 15) * 4;
#pragma unroll
  for (int i = 0; i < 4; ++i) {
    float4 v = *(const float4*)(src + (size_t)(r0 + rl + i * 16) * C + c0 + cl4);
    tile[rl + i * 16][cl4 + 0] = v.x;
    tile[rl + i * 16][cl4 + 1] = v.y;
    tile[rl + i * 16][cl4 + 2] = v.z;
    tile[rl + i * 16][cl4 + 3] = v.w;
  }
  __syncthreads();
#pragma unroll
  for (int itw = 0; itw < 2; ++itw) {
    int g  = itw * 256 + tid;       // 512 items: 64 dst rows x 8 chunks
    int c  = g >> 3;                // dst row (source column)
    int rc = g & 7;                 // 8-element chunk along source rows
    ushort8 u;
#pragma unroll
    for (int k = 0; k < 8; ++k) u[k] = f2b(tile[rc * 8 + k][c]);
    *(ushort8*)(dst + (size_t)(c0 + c) * R + r0 + rc * 8) = u;
  }
}

// ---------------------------------------------------------------------------
// Router: logits (fp32) -> softmax -> top-2; casts x to bf16; block-aggregated
// expert counts -> global atomics. Also zeroes `out` for fc2's atomic combine.
// ---------------------------------------------------------------------------
__global__ __launch_bounds__(256) void router_kernel(
    const float* __restrict__ x, const float* __restrict__ rw,
    unsigned short* __restrict__ xb, int* __restrict__ top_e, float* __restrict__ top_p,
    int* __restrict__ counts, float* __restrict__ out_zero)
{
  __shared__ float lrw[H_DIM * 9];   // padded stride 9 to spread banks
  __shared__ int lc[E_NUM];
  const int tid = threadIdx.x;
  {
    float4 z = {0.f, 0.f, 0.f, 0.f};
    float4* o4 = (float4*)out_zero;
    int base = blockIdx.x * 256 + tid;
#pragma unroll
    for (int i = 0; i < 32; ++i) o4[base + i * 65536] = z;
  }
  if (tid < E_NUM) lc[tid] = 0;
  for (int r = tid; r < H_DIM; r += 256) {
    const float* s = rw + r * 8;
    float4 a = *(const float4*)(s);
    float4 b = *(const float4*)(s + 4);
    float* d = &lrw[r * 9];
    d[0] = a.x; d[1] = a.y; d[2] = a.z; d[3] = a.w;
    d[4] = b.x; d[5] = b.y; d[6] = b.z; d[7] = b.w;
  }
  __syncthreads();
  const int lane = tid & 63, wid = tid >> 6;
  for (int i = 0; i < 8; ++i) {
    const int t = blockIdx.x * 32 + wid * 8 + i;
    float acc[8] = {0.f, 0.f, 0.f, 0.f, 0.f, 0.f, 0.f, 0.f};
    const float* xrow = x + (size_t)t * H_DIM;
    unsigned short* xbrow = xb + (size_t)t * H_DIM;
#pragma unroll
    for (int j = 0; j < 16; ++j) {
      int h = j * 64 + lane;
      float xv = xrow[h];
      xbrow[h] = f2b(xv);
      const float* rr = &lrw[h * 9];
#pragma unroll
      for (int e = 0; e < 8; ++e) acc[e] += xv * rr[e];
    }
#pragma unroll
    for (int e = 0; e < 8; ++e) {
#pragma unroll
      for (int s = 32; s > 0; s >>= 1) acc[e] += __shfl_xor(acc[e], s, 64);
    }
    if (lane == 0) {
      float mx = acc[0];
      for (int e = 1; e < 8; ++e) mx = fmaxf(mx, acc[e]);
      float p[8]; float sum = 0.f;
      for (int e = 0; e < 8; ++e) { p[e] = expf(acc[e] - mx); sum += p[e]; }
      float inv = 1.0f / sum;
      int i1 = 0; float b1 = p[0];
      for (int e = 1; e < 8; ++e) if (p[e] > b1) { b1 = p[e]; i1 = e; }
      int i2 = (i1 == 0) ? 1 : 0; float b2 = p[i2];
      for (int e = 0; e < 8; ++e) if (e != i1 && p[e] > b2) { b2 = p[e]; i2 = e; }
      top_e[2 * t]     = i1; top_p[2 * t]     = b1 * inv;
      top_e[2 * t + 1] = i2; top_p[2 * t + 1] = b2 * inv;
      atomicAdd(&lc[i1], 1);
      atomicAdd(&lc[i2], 1);
    }
  }
  __syncthreads();
  if (tid < E_NUM) atomicAdd(&counts[tid], lc[tid]);
}

// ---------------------------------------------------------------------------
// Dispatch: assign each (token, k) a slot in its expert's contiguous segment.
// ---------------------------------------------------------------------------
__global__ __launch_bounds__(256) void assign_kernel(
    const int* __restrict__ top_e, const float* __restrict__ top_p,
    const int* __restrict__ counts, int* __restrict__ cursor,
    int* __restrict__ map, float* __restrict__ gate, int* __restrict__ offsets)
{
  __shared__ int lc[E_NUM], lb[E_NUM], loff[E_NUM];
  const int tid = threadIdx.x;
  const int t = blockIdx.x * 256 + tid;
  if (tid < E_NUM) lc[tid] = 0;
  if (tid == 0) {
    int o = 0;
    for (int e = 0; e < E_NUM; ++e) { loff[e] = o; o += counts[e]; }
  }
  __syncthreads();
  int e0 = top_e[2 * t], e1 = top_e[2 * t + 1];
  int p0 = atomicAdd(&lc[e0], 1);
  int p1 = atomicAdd(&lc[e1], 1);
  __syncthreads();
  if (tid < E_NUM) lb[tid] = atomicAdd(&cursor[tid], lc[tid]);
  __syncthreads();
  int s0 = loff[e0] + lb[e0] + p0;
  int s1 = loff[e1] + lb[e1] + p1;
  map[s0] = t; gate[s0] = top_p[2 * t];
  map[s1] = t; gate[s1] = top_p[2 * t + 1];
  if (blockIdx.x == 0 && tid < E_NUM) offsets[tid] = loff[tid];
}

// ---------------------------------------------------------------------------
// fc1 GEMM, m201-faithful phased schedule adapted to 3-slot ring:
// BM=BN=256, BK=32, 512 thr = 8 waves (2M x 4N), wave-tile 128x64, acc[8][4].
// LDS 96KB = 3 ring slots x (A 16KB + B 16KB)  ->  TRUE 2-K-tile prefetch
// lead with COUNTED vmcnt(4) (never a drain mid-loop):
//   during kt: stage kt+2 (2 loads/phase); boundary waits vmcnt(4) ->
//   kt+1's 4 loads landed (issued a full K-tile ago), kt+2's stay in flight.
//   WAR-safe: slot(kt+2) == slot(kt-1), freed by the previous boundary
//   barrier (every wave's ds_reads complete before its MFMAs -> before bar).
// Per K-tile: 2 phases x {ds_read 8|4 x b128, 2 global_load_lds, barrier,
// setprio(1), 16 MFMA, setprio(0), barrier}  (m201 ratios: 2 loads/phase,
// MFMA:ds = 64:24 per 64-K, 16-MFMA clusters).
// ---------------------------------------------------------------------------
template <int KD, int ND, bool USE_MAP, bool GELU>
__global__ __launch_bounds__(512, 2) void moe_gemm_k32_kernel(
    const unsigned short* __restrict__ A, const unsigned short* __restrict__ Bt,
    const int* __restrict__ map, const float* __restrict__ gate,
    const int* __restrict__ counts, const int* __restrict__ offsets,
    unsigned short* __restrict__ C)
{
  __shared__ unsigned short ls[49152];   // 96 KB: A slots [0,24576) , B slots [24576,49152)
  const int e   = blockIdx.x;
  const int cnt = counts[e];
  const int tile_m = blockIdx.y;
  if (tile_m * 256 >= cnt) return;
  const int off    = offsets[e];
  const int tile_n = blockIdx.z;
  const int tid    = threadIdx.x;       // 0..511

  // Staging sources: chunk g = it*512+tid ; row = g>>2 (0..255, 4 chunks of
  // 8 bf16 per 32-K row); src chunk = (g&3) ^ (row&3)  (XOR swizzle so the
  // linear LDS image holds the swizzled layout; fragment read de-swizzles).
  const unsigned short* aSrc[2];
  const unsigned short* bSrc[2];
#pragma unroll
  for (int it = 0; it < 2; ++it) {
    int g   = it * 512 + tid;
    int row = g >> 2;
    int cs  = (g & 3) ^ (row & 3);
    int rm  = tile_m * 256 + row;
    if (rm > cnt - 1) rm = cnt - 1;               // clamp padded rows
    int arow = USE_MAP ? map[off + rm] : (off + rm);
    aSrc[it] = A + (size_t)arow * KD + cs * 8;
    int rn = tile_n * 256 + row;
    bSrc[it] = Bt + (size_t)e * ND * KD + (size_t)rn * KD + cs * 8;
  }

  const int lane = tid & 63;
  const int wid  = tid >> 6;
  const int wm = wid >> 2, wn = wid & 3;          // 2x4 wave grid, 128x64 each
  const int lr = lane & 15, kg = lane >> 4;
  const int kc = ((kg ^ (lr & 3)) * 8);           // de-swizzled k-chunk (shorts)

  f32x4 acc[8][4];
#pragma unroll
  for (int mi = 0; mi < 8; ++mi)
#pragma unroll
    for (int ni = 0; ni < 4; ++ni) acc[mi][ni] = (f32x4){0.f, 0.f, 0.f, 0.f};

  constexpr int NK = KD / 32;

  auto STAGE_A = [&](int kt, int slot) {
    const int kof = kt * 32;
#pragma unroll
    for (int it = 0; it < 2; ++it)
      __builtin_amdgcn_global_load_lds(AS_GLOBAL(aSrc[it] + kof),
          AS_LDS(ls + slot * 8192 + (it * 512 + tid) * 8), 16, 0, 0);
  };
  auto STAGE_B = [&](int kt, int slot) {
    const int kof = kt * 32;
#pragma unroll
    for (int it = 0; it < 2; ++it)
      __builtin_amdgcn_global_load_lds(AS_GLOBAL(bSrc[it] + kof),
          AS_LDS(ls + 24576 + slot * 8192 + (it * 512 + tid) * 8), 16, 0, 0);
  };

  // prologue: kt0 -> slot0, kt1 -> slot1; wait kt0 only (kt1 stays in flight)
  STAGE_A(0, 0); STAGE_B(0, 0);
  STAGE_A(1, 1); STAGE_B(1, 1);
  asm volatile("s_waitcnt vmcnt(4)" ::: "memory");
  asm volatile("s_barrier" ::: "memory");

  int sc = 0;          // slot of current K-tile kt
  int st = 2;          // slot of kt+2
#pragma unroll 1
  for (int kt = 0; kt < NK; ++kt) {
    const bool stg = (kt + 2 < NK);
    const unsigned short* pA = ls + sc * 8192 + (wm * 128 + lr) * 32;
    const unsigned short* pB = ls + 24576 + sc * 8192 + (wn * 64 + lr) * 32;
    bf16x8 aF[4], bF[4];

    // ---- phase 0: mi 0..3 (+ B frags, reused in phase 1) ----
#pragma unroll
    for (int ni = 0; ni < 4; ++ni)
      bF[ni] = *(const bf16x8*)(pB + ni * 16 * 32 + kc);
#pragma unroll
    for (int j = 0; j < 4; ++j)
      aF[j] = *(const bf16x8*)(pA + j * 16 * 32 + kc);
    if (stg) STAGE_A(kt + 2, st);
    asm volatile("s_barrier" ::: "memory");
    __builtin_amdgcn_s_setprio(1);
#pragma unroll
    for (int j = 0; j < 4; ++j)
#pragma unroll
      for (int ni = 0; ni < 4; ++ni)
        acc[j][ni] = __builtin_amdgcn_mfma_f32_16x16x32_bf16(aF[j], bF[ni], acc[j][ni], 0, 0, 0);
    __builtin_amdgcn_s_setprio(0);
    asm volatile("s_barrier" ::: "memory");

    // ---- phase 1: mi 4..7 (reuse bF) ----
#pragma unroll
    for (int j = 0; j < 4; ++j)
      aF[j] = *(const bf16x8*)(pA + (4 + j) * 16 * 32 + kc);
    if (stg) STAGE_B(kt + 2, st);
    asm volatile("s_barrier" ::: "memory");
    __builtin_amdgcn_s_setprio(1);
#pragma unroll
    for (int j = 0; j < 4; ++j)
#pragma unroll
      for (int ni = 0; ni < 4; ++ni)
        acc[4 + j][ni] = __builtin_amdgcn_mfma_f32_16x16x32_bf16(aF[j], bF[ni], acc[4 + j][ni], 0, 0, 0);
    __builtin_amdgcn_s_setprio(0);
    // boundary: counted wait -- kt+1's 4 loads landed, kt+2's 4 in flight
    if (stg) {
      asm volatile("s_waitcnt vmcnt(4)" ::: "memory");
    } else if (kt + 1 < NK) {
      asm volatile("s_waitcnt vmcnt(0)" ::: "memory");   // tail drain (cheap)
    }
    asm volatile("s_barrier" ::: "memory");
    sc = (sc == 2) ? 0 : sc + 1;
    st = (st == 2) ? 0 : st + 1;
  }

  // ---- Epilogue: gelu -> LDS repack (2 row-half passes) -> 16B stores ----
  __syncthreads();
#pragma unroll
  for (int h = 0; h < 2; ++h) {
    if (h) __syncthreads();                 // store pass h-1 done before overwrite
    if (wm == h) {
#pragma unroll
      for (int mi = 0; mi < 8; ++mi) {
#pragma unroll
        for (int r = 0; r < 4; ++r) {
          int Rl = mi * 16 + kg * 4 + r;    // 0..127 within the half
#pragma unroll
          for (int ni = 0; ni < 4; ++ni) {
            int col = wn * 64 + ni * 16 + lr;
            float v = acc[mi][ni][r];
            v = GELU ? gelu_fast(v) : v;
            ls[Rl * 264 + col] = f2b(v);
          }
        }
      }
    }
    __syncthreads();
#pragma unroll
    for (int it = 0; it < 8; ++it) {
      int g = it * 512 + tid;               // 128 rows x 32 chunks of 8
      int R = g >> 5, c8 = g & 31;
      int gm = tile_m * 256 + h * 128 + R;
      if (gm < cnt) {
        ushort8 v = *(const ushort8*)(ls + R * 264 + c8 * 8);
        *(ushort8*)(C + (size_t)(off + gm) * ND + tile_n * 256 + c8 * 8) = v;
      }
    }
  }
}

// ---------------------------------------------------------------------------
// fc2 GEMM (control, unchanged): 128x128 tile, BK=64, 4 waves of 64x64.
// ATOMIC_OUT epilogue: gated fp32 atomicAdd into out[token] (fused combine).
// ---------------------------------------------------------------------------
template <int KD, int ND, bool USE_MAP, bool GELU, bool ATOMIC_OUT>
__global__ __launch_bounds__(256) void moe_gemm_kernel(
    const unsigned short* __restrict__ A, const unsigned short* __restrict__ Bt,
    const int* __restrict__ map, const float* __restrict__ gate,
    const int* __restrict__ counts, const int* __restrict__ offsets,
    unsigned short* __restrict__ C, float* __restrict__ out)
{
  __shared__ unsigned short ls[32768];           // 64 KB: [A0|A1|B0|B1] 8192 shorts each
  const int e   = blockIdx.x;
  const int cnt = counts[e];
  const int tile_m = blockIdx.y;
  if (tile_m * 128 >= cnt) return;
  const int off    = offsets[e];
  const int tile_n = blockIdx.z;
  const int tid    = threadIdx.x;

  const unsigned short* aSrc[4];
  const unsigned short* bSrc[4];
  const int cswz = ((tid & 7) ^ ((tid >> 3) & 7)) * 8;
#pragma unroll
  for (int it = 0; it < 4; ++it) {
    int r  = it * 32 + (tid >> 3);
    int rm = tile_m * 128 + r;
    if (rm > cnt - 1) rm = cnt - 1;               // clamp padded rows
    int arow = USE_MAP ? map[off + rm] : (off + rm);
    aSrc[it] = A + (size_t)arow * KD + cswz;
    int rn = tile_n * 128 + r;
    bSrc[it] = Bt + (size_t)e * ND * KD + (size_t)rn * KD + cswz;
  }

  const int lane = tid & 63;
  const int wid  = tid >> 6;
  const int wm = wid >> 1, wn = wid & 1;          // 2x2 wave grid, 64x64 each
  const int lr = lane & 15, kg = lane >> 4;
  const int swz = lr & 7;                          // fragment read de-swizzle

  f32x4 acc[4][4];
#pragma unroll
  for (int mi = 0; mi < 4; ++mi)
#pragma unroll
    for (int ni = 0; ni < 4; ++ni) acc[mi][ni] = (f32x4){0.f, 0.f, 0.f, 0.f};

  constexpr int NK = KD / 64;

#pragma unroll
  for (int it = 0; it < 4; ++it)
    __builtin_amdgcn_global_load_lds(AS_GLOBAL(aSrc[it]),
                                     AS_LDS(ls + (it * 256 + tid) * 8), 16, 0, 0);
#pragma unroll
  for (int it = 0; it < 4; ++it)
    __builtin_amdgcn_global_load_lds(AS_GLOBAL(bSrc[it]),
                                     AS_LDS(ls + 16384 + (it * 256 + tid) * 8), 16, 0, 0);

#pragma unroll 1
  for (int k = 0; k < NK; ++k) {
    const int p = k & 1;
    asm volatile("s_barrier" ::: "memory");
    if (k + 1 < NK) {
      const int q = p ^ 1;
      const int k0 = (k + 1) * 64;
#pragma unroll
      for (int it = 0; it < 4; ++it)
        __builtin_amdgcn_global_load_lds(AS_GLOBAL(aSrc[it] + k0),
                                         AS_LDS(ls + q * 8192 + (it * 256 + tid) * 8), 16, 0, 0);
#pragma unroll
      for (int it = 0; it < 4; ++it)
        __builtin_amdgcn_global_load_lds(AS_GLOBAL(bSrc[it] + k0),
                                         AS_LDS(ls + 16384 + q * 8192 + (it * 256 + tid) * 8), 16, 0, 0);
      asm volatile("s_waitcnt vmcnt(8)" ::: "memory");   // wait iter-k loads only
    } else {
      asm volatile("s_waitcnt vmcnt(0)" ::: "memory");
    }
    asm volatile("s_barrier" ::: "memory");

    const unsigned short* pA = ls + p * 8192 + (wm * 64 + lr) * 64;
    const unsigned short* pB = ls + 16384 + p * 8192 + (wn * 64 + lr) * 64;
#pragma unroll
    for (int ks = 0; ks < 2; ++ks) {
      bf16x8 aF[4], bF[4];
#pragma unroll
      for (int i = 0; i < 4; ++i)
        aF[i] = *(const bf16x8*)(pA + i * 16 * 64 + (((ks * 4 + kg) ^ swz) * 8));
#pragma unroll
      for (int i = 0; i < 4; ++i)
        bF[i] = *(const bf16x8*)(pB + i * 16 * 64 + (((ks * 4 + kg) ^ swz) * 8));
#pragma unroll
      for (int mi = 0; mi < 4; ++mi)
#pragma unroll
        for (int ni = 0; ni < 4; ++ni)
          acc[mi][ni] = __builtin_amdgcn_mfma_f32_16x16x32_bf16(aF[mi], bF[ni],
                                                                acc[mi][ni], 0, 0, 0);
    }
  }

  if (ATOMIC_OUT) {
#pragma unroll
    for (int mi = 0; mi < 4; ++mi) {
#pragma unroll
      for (int r = 0; r < 4; ++r) {
        int Rl = wm * 64 + mi * 16 + kg * 4 + r;
        int gm = tile_m * 128 + Rl;
        if (gm < cnt) {
          int   t  = map[off + gm];
          float gv = gate[off + gm];
          float* orow = out + (size_t)t * ND + tile_n * 128 + wn * 64 + lr;
#pragma unroll
          for (int ni = 0; ni < 4; ++ni)
            __hip_atomic_fetch_add(orow + ni * 16, acc[mi][ni][r] * gv,
                                   __ATOMIC_RELAXED, __HIP_MEMORY_SCOPE_AGENT);
        }
      }
    }
  } else {
    __syncthreads();
#pragma unroll
    for (int mi = 0; mi < 4; ++mi) {
#pragma unroll
      for (int r = 0; r < 4; ++r) {
        int Rl = wm * 64 + mi * 16 + kg * 4 + r;
#pragma unroll
        for (int ni = 0; ni < 4; ++ni) {
          int col = wn * 64 + ni * 16 + lr;
          float v = acc[mi][ni][r];
          v = GELU ? gelu_fast(v) : v;
          ls[Rl * 136 + col] = f2b(v);
        }
      }
    }
    __syncthreads();
#pragma unroll
    for (int it = 0; it < 8; ++it) {
      int g = it * 256 + tid;
      int R = g >> 4, c16 = g & 15;
      int gm = tile_m * 128 + R;
      if (gm < cnt) {
        ushort8 v = *(const ushort8*)(ls + R * 136 + c16 * 8);
        *(ushort8*)(C + (size_t)(off + gm) * ND + tile_n * 128 + c16 * 8) = v;
      }
    }
  }
}

// ---------------------------------------------------------------------------
extern "C" void kernel_launch(void* const* d_in, const int* in_sizes, int n_in,
                              void* d_out, int out_size, void* d_ws, size_t ws_size,
                              hipStream_t stream) {
  const float* x  = (const float*)d_in[0];   // [S,B,H] = [8192,1024]
  const float* rw = (const float*)d_in[1];   // [H,E]   = [1024,8]
  const float* w1 = (const float*)d_in[2];   // [E,H,F]
  const float* w2 = (const float*)d_in[3];   // [E,F,H]
  float* out = (float*)d_out;

  char* ws = (char*)d_ws;
  unsigned short* wT     = (unsigned short*)ws;                     // 64 MB (w1t, then w2t)
  unsigned short* xb     = (unsigned short*)(ws + (64ull  << 20));  // 16 MB
  unsigned short* hidden = (unsigned short*)(ws + (96ull  << 20));  // 128 MB
  char* meta = ws + (224ull << 20);
  int*   top_e   = (int*)meta;                     // 16384
  float* top_p   = (float*)(meta + (64 << 10));    // 16384
  int*   map     = (int*)(meta + (128 << 10));     // 16384
  float* gate    = (float*)(meta + (192 << 10));   // 16384
  int*   counts  = (int*)(meta + (320 << 10));     // 8
  int*   offsets = counts + 8;
  int*   cursor  = counts + 16;

  // 1. w1 [E][H][F] fp32 -> wT = w1t [E][F][H] bf16  (+ zero 24 meta words)
  transpose_cast_kernel<<<dim3(F_DIM / 64, H_DIM / 64, E_NUM), 256, 0, stream>>>(
      w1, wT, H_DIM, F_DIM, counts);
  // 2. router (+ x -> bf16, + per-block expert counts, + zero out[])
  router_kernel<<<256, 256, 0, stream>>>(x, rw, xb, top_e, top_p, counts, out);
  // 3. slot assignment (+ per-block offsets from counts; block 0 publishes)
  assign_kernel<<<T_TOKENS / 256, 256, 0, stream>>>(top_e, top_p, counts, cursor,
                                                    map, gate, offsets);
  // 4. fc1: hidden = gelu(x @ w1[e])  (256x256 BK=32 3-slot phased kernel)
  moe_gemm_k32_kernel<H_DIM, F_DIM, true, true>
      <<<dim3(E_NUM, 32, F_DIM / 256), 512, 0, stream>>>(xb, wT, map, gate,
                                                         counts, offsets, hidden);
  // 5. w2 [E][F][H] fp32 -> wT = w2t [E][H][F] bf16 (wT free after fc1)
  transpose_cast_kernel<<<dim3(H_DIM / 64, F_DIM / 64, E_NUM), 256, 0, stream>>>(
      w2, wT, F_DIM, H_DIM, nullptr);
  // 6. fc2 (control): out[t] += gate * (hidden @ w2[e])  (fused combine)
  moe_gemm_kernel<F_DIM, H_DIM, false, false, true>
      <<<dim3(E_NUM, 64, H_DIM / 128), 256, 0, stream>>>(hidden, wT, map, gate,
                                                         counts, offsets, nullptr, out);
}

// Round 4
// 740.547 us; speedup vs baseline: 1.1155x; 1.1155x over previous
//
#include <hip/hip_runtime.h>
#include <cstdint>
#include <cstddef>

// Problem dims (fixed)
#define T_TOKENS 8192
#define H_DIM    1024
#define F_DIM    4096
#define E_NUM    8

typedef __bf16 bf16x8 __attribute__((ext_vector_type(8)));
typedef float  f32x4  __attribute__((ext_vector_type(4)));
typedef unsigned short ushort8 __attribute__((ext_vector_type(8)));

#define AS_GLOBAL(p) ((const __attribute__((address_space(1))) void*)(p))
#define AS_LDS(p)    ((__attribute__((address_space(3))) void*)(p))

__device__ inline unsigned short f2b(float f) {
  unsigned int u = __float_as_uint(f);
  unsigned int r = (u + 0x7fffu + ((u >> 16) & 1u)) >> 16;   // RNE
  return (unsigned short)r;
}
__device__ inline float b2f(unsigned short u) {
  return __uint_as_float(((unsigned int)u) << 16);
}
// gelu(v) = 0.5 v (1 + tanh(u)) = v * sigmoid(2u), u = 0.79788456(v + 0.044715 v^3)
__device__ inline float gelu_fast(float v) {
  float u2 = 1.5957691216057308f * v * (1.0f + 0.044715f * v * v);
  return v / (1.0f + __expf(-u2));
}

// ---------------------------------------------------------------------------
// Transpose + fp32->bf16 cast:  in [E][R][C] fp32  ->  out [E][C][R] bf16
// ushort8 (16B) stores. Also zeroes the 24-word routing meta block when
// zc != nullptr (folds the old zero_meta launch; stream-ordered before router).
// ---------------------------------------------------------------------------
__global__ __launch_bounds__(256) void transpose_cast_kernel(
    const float* __restrict__ in, unsigned short* __restrict__ out, int R, int C,
    int* __restrict__ zc)
{
  __shared__ float tile[64][65];
  const int tid = threadIdx.x;
  if (zc && blockIdx.x == 0 && blockIdx.y == 0 && blockIdx.z == 0 && tid < 24)
    zc[tid] = 0;
  const int e  = blockIdx.z;
  const int c0 = blockIdx.x * 64;
  const int r0 = blockIdx.y * 64;
  const float* src = in + (size_t)e * R * C;
  unsigned short* dst = out + (size_t)e * R * C;
  const int rl  = tid >> 4;
  const int cl4 = (tid & 15) * 4;
#pragma unroll
  for (int i = 0; i < 4; ++i) {
    float4 v = *(const float4*)(src + (size_t)(r0 + rl + i * 16) * C + c0 + cl4);
    tile[rl + i * 16][cl4 + 0] = v.x;
    tile[rl + i * 16][cl4 + 1] = v.y;
    tile[rl + i * 16][cl4 + 2] = v.z;
    tile[rl + i * 16][cl4 + 3] = v.w;
  }
  __syncthreads();
#pragma unroll
  for (int itw = 0; itw < 2; ++itw) {
    int g  = itw * 256 + tid;       // 512 items: 64 dst rows x 8 chunks
    int c  = g >> 3;                // dst row (source column)
    int rc = g & 7;                 // 8-element chunk along source rows
    ushort8 u;
#pragma unroll
    for (int k = 0; k < 8; ++k) u[k] = f2b(tile[rc * 8 + k][c]);
    *(ushort8*)(dst + (size_t)(c0 + c) * R + r0 + rc * 8) = u;
  }
}

// ---------------------------------------------------------------------------
// Router: logits (fp32) -> softmax -> top-2; casts x to bf16; block-aggregated
// expert counts -> global atomics.
// ---------------------------------------------------------------------------
__global__ __launch_bounds__(256) void router_kernel(
    const float* __restrict__ x, const float* __restrict__ rw,
    unsigned short* __restrict__ xb, int* __restrict__ top_e, float* __restrict__ top_p,
    int* __restrict__ counts)
{
  __shared__ float lrw[H_DIM * 9];   // padded stride 9 to spread banks
  __shared__ int lc[E_NUM];
  const int tid = threadIdx.x;
  if (tid < E_NUM) lc[tid] = 0;
  for (int r = tid; r < H_DIM; r += 256) {
    const float* s = rw + r * 8;
    float4 a = *(const float4*)(s);
    float4 b = *(const float4*)(s + 4);
    float* d = &lrw[r * 9];
    d[0] = a.x; d[1] = a.y; d[2] = a.z; d[3] = a.w;
    d[4] = b.x; d[5] = b.y; d[6] = b.z; d[7] = b.w;
  }
  __syncthreads();
  const int lane = tid & 63, wid = tid >> 6;
  for (int i = 0; i < 8; ++i) {
    const int t = blockIdx.x * 32 + wid * 8 + i;
    float acc[8] = {0.f, 0.f, 0.f, 0.f, 0.f, 0.f, 0.f, 0.f};
    const float* xrow = x + (size_t)t * H_DIM;
    unsigned short* xbrow = xb + (size_t)t * H_DIM;
#pragma unroll
    for (int j = 0; j < 16; ++j) {
      int h = j * 64 + lane;
      float xv = xrow[h];
      xbrow[h] = f2b(xv);
      const float* rr = &lrw[h * 9];
#pragma unroll
      for (int e = 0; e < 8; ++e) acc[e] += xv * rr[e];
    }
#pragma unroll
    for (int e = 0; e < 8; ++e) {
#pragma unroll
      for (int s = 32; s > 0; s >>= 1) acc[e] += __shfl_xor(acc[e], s, 64);
    }
    if (lane == 0) {
      float mx = acc[0];
      for (int e = 1; e < 8; ++e) mx = fmaxf(mx, acc[e]);
      float p[8]; float sum = 0.f;
      for (int e = 0; e < 8; ++e) { p[e] = expf(acc[e] - mx); sum += p[e]; }
      float inv = 1.0f / sum;
      int i1 = 0; float b1 = p[0];
      for (int e = 1; e < 8; ++e) if (p[e] > b1) { b1 = p[e]; i1 = e; }
      int i2 = (i1 == 0) ? 1 : 0; float b2 = p[i2];
      for (int e = 0; e < 8; ++e) if (e != i1 && p[e] > b2) { b2 = p[e]; i2 = e; }
      top_e[2 * t]     = i1; top_p[2 * t]     = b1 * inv;
      top_e[2 * t + 1] = i2; top_p[2 * t + 1] = b2 * inv;
      atomicAdd(&lc[i1], 1);
      atomicAdd(&lc[i2], 1);
    }
  }
  __syncthreads();
  if (tid < E_NUM) atomicAdd(&counts[tid], lc[tid]);
}

// ---------------------------------------------------------------------------
// Dispatch: assign each (token, k) a slot in its expert's contiguous segment.
// Offsets computed per-block from counts (folds the old offsets_kernel);
// block 0 publishes offsets[] for the GEMMs. slot_of feeds combine.
// ---------------------------------------------------------------------------
__global__ __launch_bounds__(256) void assign_kernel(
    const int* __restrict__ top_e, const float* __restrict__ top_p,
    const int* __restrict__ counts, int* __restrict__ cursor,
    int* __restrict__ map, float* __restrict__ gate, int* __restrict__ slot_of,
    int* __restrict__ offsets)
{
  __shared__ int lc[E_NUM], lb[E_NUM], loff[E_NUM];
  const int tid = threadIdx.x;
  const int t = blockIdx.x * 256 + tid;
  if (tid < E_NUM) lc[tid] = 0;
  if (tid == 0) {
    int o = 0;
    for (int e = 0; e < E_NUM; ++e) { loff[e] = o; o += counts[e]; }
  }
  __syncthreads();
  int e0 = top_e[2 * t], e1 = top_e[2 * t + 1];
  int p0 = atomicAdd(&lc[e0], 1);
  int p1 = atomicAdd(&lc[e1], 1);
  __syncthreads();
  if (tid < E_NUM) lb[tid] = atomicAdd(&cursor[tid], lc[tid]);
  __syncthreads();
  int s0 = loff[e0] + lb[e0] + p0;
  int s1 = loff[e1] + lb[e1] + p1;
  map[s0] = t; gate[s0] = top_p[2 * t];
  map[s1] = t; gate[s1] = top_p[2 * t + 1];
  slot_of[2 * t] = s0; slot_of[2 * t + 1] = s1;
  if (blockIdx.x == 0 && tid < E_NUM) offsets[tid] = loff[tid];
}

// ---------------------------------------------------------------------------
// fc1 GEMM (proven 209us config): 128x128 tile, BK=64, 4 waves of 64x64,
// mfma 16x16x32 bf16. Double-buffered LDS, counted vmcnt(8), raw s_barrier,
// chunk-XOR swizzle. GELU epilogue -> LDS repack -> coalesced 16B stores.
// ---------------------------------------------------------------------------
template <int KD, int ND, bool USE_MAP>
__global__ __launch_bounds__(256) void moe_gemm_kernel(
    const unsigned short* __restrict__ A, const unsigned short* __restrict__ Bt,
    const int* __restrict__ map,
    const int* __restrict__ counts, const int* __restrict__ offsets,
    unsigned short* __restrict__ C)
{
  __shared__ unsigned short ls[32768];           // 64 KB: [A0|A1|B0|B1] 8192 shorts each
  const int e   = blockIdx.x;
  const int cnt = counts[e];
  const int tile_m = blockIdx.y;
  if (tile_m * 128 >= cnt) return;
  const int off    = offsets[e];
  const int tile_n = blockIdx.z;
  const int tid    = threadIdx.x;

  const unsigned short* aSrc[4];
  const unsigned short* bSrc[4];
  const int cswz = ((tid & 7) ^ ((tid >> 3) & 7)) * 8;
#pragma unroll
  for (int it = 0; it < 4; ++it) {
    int r  = it * 32 + (tid >> 3);
    int rm = tile_m * 128 + r;
    if (rm > cnt - 1) rm = cnt - 1;               // clamp padded rows
    int arow = USE_MAP ? map[off + rm] : (off + rm);
    aSrc[it] = A + (size_t)arow * KD + cswz;
    int rn = tile_n * 128 + r;
    bSrc[it] = Bt + (size_t)e * ND * KD + (size_t)rn * KD + cswz;
  }

  const int lane = tid & 63;
  const int wid  = tid >> 6;
  const int wm = wid >> 1, wn = wid & 1;          // 2x2 wave grid, 64x64 each
  const int lr = lane & 15, kg = lane >> 4;
  const int swz = lr & 7;                          // fragment read de-swizzle

  f32x4 acc[4][4];
#pragma unroll
  for (int mi = 0; mi < 4; ++mi)
#pragma unroll
    for (int ni = 0; ni < 4; ++ni) acc[mi][ni] = (f32x4){0.f, 0.f, 0.f, 0.f};

  constexpr int NK = KD / 64;

#pragma unroll
  for (int it = 0; it < 4; ++it)
    __builtin_amdgcn_global_load_lds(AS_GLOBAL(aSrc[it]),
                                     AS_LDS(ls + (it * 256 + tid) * 8), 16, 0, 0);
#pragma unroll
  for (int it = 0; it < 4; ++it)
    __builtin_amdgcn_global_load_lds(AS_GLOBAL(bSrc[it]),
                                     AS_LDS(ls + 16384 + (it * 256 + tid) * 8), 16, 0, 0);

#pragma unroll 1
  for (int k = 0; k < NK; ++k) {
    const int p = k & 1;
    asm volatile("s_barrier" ::: "memory");
    if (k + 1 < NK) {
      const int q = p ^ 1;
      const int k0 = (k + 1) * 64;
#pragma unroll
      for (int it = 0; it < 4; ++it)
        __builtin_amdgcn_global_load_lds(AS_GLOBAL(aSrc[it] + k0),
                                         AS_LDS(ls + q * 8192 + (it * 256 + tid) * 8), 16, 0, 0);
#pragma unroll
      for (int it = 0; it < 4; ++it)
        __builtin_amdgcn_global_load_lds(AS_GLOBAL(bSrc[it] + k0),
                                         AS_LDS(ls + 16384 + q * 8192 + (it * 256 + tid) * 8), 16, 0, 0);
      asm volatile("s_waitcnt vmcnt(8)" ::: "memory");   // wait iter-k loads only
    } else {
      asm volatile("s_waitcnt vmcnt(0)" ::: "memory");
    }
    asm volatile("s_barrier" ::: "memory");

    const unsigned short* pA = ls + p * 8192 + (wm * 64 + lr) * 64;
    const unsigned short* pB = ls + 16384 + p * 8192 + (wn * 64 + lr) * 64;
#pragma unroll
    for (int ks = 0; ks < 2; ++ks) {
      bf16x8 aF[4], bF[4];
#pragma unroll
      for (int i = 0; i < 4; ++i)
        aF[i] = *(const bf16x8*)(pA + i * 16 * 64 + (((ks * 4 + kg) ^ swz) * 8));
#pragma unroll
      for (int i = 0; i < 4; ++i)
        bF[i] = *(const bf16x8*)(pB + i * 16 * 64 + (((ks * 4 + kg) ^ swz) * 8));
#pragma unroll
      for (int mi = 0; mi < 4; ++mi)
#pragma unroll
        for (int ni = 0; ni < 4; ++ni)
          acc[mi][ni] = __builtin_amdgcn_mfma_f32_16x16x32_bf16(aF[mi], bF[ni],
                                                                acc[mi][ni], 0, 0, 0);
    }
  }

  // ---- epilogue: gelu -> LDS repack -> coalesced 16B bf16 stores ----
  __syncthreads();
#pragma unroll
  for (int mi = 0; mi < 4; ++mi) {
#pragma unroll
    for (int r = 0; r < 4; ++r) {
      int Rl = wm * 64 + mi * 16 + kg * 4 + r;
#pragma unroll
      for (int ni = 0; ni < 4; ++ni) {
        int col = wn * 64 + ni * 16 + lr;
        ls[Rl * 136 + col] = f2b(gelu_fast(acc[mi][ni][r]));
      }
    }
  }
  __syncthreads();
#pragma unroll
  for (int it = 0; it < 8; ++it) {
    int g = it * 256 + tid;
    int R = g >> 4, c16 = g & 15;
    int gm = tile_m * 128 + R;
    if (gm < cnt) {
      ushort8 v = *(const ushort8*)(ls + R * 136 + c16 * 8);
      *(ushort8*)(C + (size_t)(off + gm) * ND + tile_n * 128 + c16 * 8) = v;
    }
  }
}

// ---------------------------------------------------------------------------
// fc2 GEMM (same proven structure, distinct name for rocprof visibility):
// gate applied in epilogue, bf16 y stores; combine sums the two slots.
// ---------------------------------------------------------------------------
template <int KD, int ND>
__global__ __launch_bounds__(256) void moe_gemm_fc2_kernel(
    const unsigned short* __restrict__ A, const unsigned short* __restrict__ Bt,
    const float* __restrict__ gate,
    const int* __restrict__ counts, const int* __restrict__ offsets,
    unsigned short* __restrict__ C)
{
  __shared__ unsigned short ls[32768];
  const int e   = blockIdx.x;
  const int cnt = counts[e];
  const int tile_m = blockIdx.y;
  if (tile_m * 128 >= cnt) return;
  const int off    = offsets[e];
  const int tile_n = blockIdx.z;
  const int tid    = threadIdx.x;

  const unsigned short* aSrc[4];
  const unsigned short* bSrc[4];
  const int cswz = ((tid & 7) ^ ((tid >> 3) & 7)) * 8;
#pragma unroll
  for (int it = 0; it < 4; ++it) {
    int r  = it * 32 + (tid >> 3);
    int rm = tile_m * 128 + r;
    if (rm > cnt - 1) rm = cnt - 1;
    aSrc[it] = A + (size_t)(off + rm) * KD + cswz;
    int rn = tile_n * 128 + r;
    bSrc[it] = Bt + (size_t)e * ND * KD + (size_t)rn * KD + cswz;
  }

  const int lane = tid & 63;
  const int wid  = tid >> 6;
  const int wm = wid >> 1, wn = wid & 1;
  const int lr = lane & 15, kg = lane >> 4;
  const int swz = lr & 7;

  f32x4 acc[4][4];
#pragma unroll
  for (int mi = 0; mi < 4; ++mi)
#pragma unroll
    for (int ni = 0; ni < 4; ++ni) acc[mi][ni] = (f32x4){0.f, 0.f, 0.f, 0.f};

  constexpr int NK = KD / 64;

#pragma unroll
  for (int it = 0; it < 4; ++it)
    __builtin_amdgcn_global_load_lds(AS_GLOBAL(aSrc[it]),
                                     AS_LDS(ls + (it * 256 + tid) * 8), 16, 0, 0);
#pragma unroll
  for (int it = 0; it < 4; ++it)
    __builtin_amdgcn_global_load_lds(AS_GLOBAL(bSrc[it]),
                                     AS_LDS(ls + 16384 + (it * 256 + tid) * 8), 16, 0, 0);

#pragma unroll 1
  for (int k = 0; k < NK; ++k) {
    const int p = k & 1;
    asm volatile("s_barrier" ::: "memory");
    if (k + 1 < NK) {
      const int q = p ^ 1;
      const int k0 = (k + 1) * 64;
#pragma unroll
      for (int it = 0; it < 4; ++it)
        __builtin_amdgcn_global_load_lds(AS_GLOBAL(aSrc[it] + k0),
                                         AS_LDS(ls + q * 8192 + (it * 256 + tid) * 8), 16, 0, 0);
#pragma unroll
      for (int it = 0; it < 4; ++it)
        __builtin_amdgcn_global_load_lds(AS_GLOBAL(bSrc[it] + k0),
                                         AS_LDS(ls + 16384 + q * 8192 + (it * 256 + tid) * 8), 16, 0, 0);
      asm volatile("s_waitcnt vmcnt(8)" ::: "memory");
    } else {
      asm volatile("s_waitcnt vmcnt(0)" ::: "memory");
    }
    asm volatile("s_barrier" ::: "memory");

    const unsigned short* pA = ls + p * 8192 + (wm * 64 + lr) * 64;
    const unsigned short* pB = ls + 16384 + p * 8192 + (wn * 64 + lr) * 64;
#pragma unroll
    for (int ks = 0; ks < 2; ++ks) {
      bf16x8 aF[4], bF[4];
#pragma unroll
      for (int i = 0; i < 4; ++i)
        aF[i] = *(const bf16x8*)(pA + i * 16 * 64 + (((ks * 4 + kg) ^ swz) * 8));
#pragma unroll
      for (int i = 0; i < 4; ++i)
        bF[i] = *(const bf16x8*)(pB + i * 16 * 64 + (((ks * 4 + kg) ^ swz) * 8));
#pragma unroll
      for (int mi = 0; mi < 4; ++mi)
#pragma unroll
        for (int ni = 0; ni < 4; ++ni)
          acc[mi][ni] = __builtin_amdgcn_mfma_f32_16x16x32_bf16(aF[mi], bF[ni],
                                                                acc[mi][ni], 0, 0, 0);
    }
  }

  // ---- epilogue: gate -> LDS repack -> coalesced 16B bf16 stores ----
  __syncthreads();
#pragma unroll
  for (int mi = 0; mi < 4; ++mi) {
#pragma unroll
    for (int r = 0; r < 4; ++r) {
      int Rl = wm * 64 + mi * 16 + kg * 4 + r;
      int gm = tile_m * 128 + Rl;
      int gmc = gm < cnt ? gm : cnt - 1;
      float gv = gate[off + gmc];
#pragma unroll
      for (int ni = 0; ni < 4; ++ni) {
        int col = wn * 64 + ni * 16 + lr;
        ls[Rl * 136 + col] = f2b(acc[mi][ni][r] * gv);
      }
    }
  }
  __syncthreads();
#pragma unroll
  for (int it = 0; it < 8; ++it) {
    int g = it * 256 + tid;
    int R = g >> 4, c16 = g & 15;
    int gm = tile_m * 128 + R;
    if (gm < cnt) {
      ushort8 v = *(const ushort8*)(ls + R * 136 + c16 * 8);
      *(ushort8*)(C + (size_t)(off + gm) * ND + tile_n * 128 + c16 * 8) = v;
    }
  }
}

// ---------------------------------------------------------------------------
// Combine: out[t] = y[slot0(t)] + y[slot1(t)]   (gates already applied)
// ---------------------------------------------------------------------------
__global__ __launch_bounds__(256) void combine_kernel(
    const unsigned short* __restrict__ y, const int* __restrict__ slot_of,
    float* __restrict__ out)
{
  const int t  = blockIdx.x;
  const int h0 = threadIdx.x * 4;
  const int s0 = slot_of[2 * t], s1 = slot_of[2 * t + 1];
  ushort4 a = *(const ushort4*)(y + (size_t)s0 * H_DIM + h0);
  ushort4 b = *(const ushort4*)(y + (size_t)s1 * H_DIM + h0);
  float4 o;
  o.x = b2f(a.x) + b2f(b.x);
  o.y = b2f(a.y) + b2f(b.y);
  o.z = b2f(a.z) + b2f(b.z);
  o.w = b2f(a.w) + b2f(b.w);
  *(float4*)(out + (size_t)t * H_DIM + h0) = o;
}

// ---------------------------------------------------------------------------
extern "C" void kernel_launch(void* const* d_in, const int* in_sizes, int n_in,
                              void* d_out, int out_size, void* d_ws, size_t ws_size,
                              hipStream_t stream) {
  const float* x  = (const float*)d_in[0];   // [S,B,H] = [8192,1024]
  const float* rw = (const float*)d_in[1];   // [H,E]   = [1024,8]
  const float* w1 = (const float*)d_in[2];   // [E,H,F]
  const float* w2 = (const float*)d_in[3];   // [E,F,H]
  float* out = (float*)d_out;

  char* ws = (char*)d_ws;
  unsigned short* wT     = (unsigned short*)ws;                     // 64 MB (w1t, then w2t)
  unsigned short* xb     = (unsigned short*)(ws + (64ull  << 20));  // 16 MB
  unsigned short* y      = (unsigned short*)(ws + (64ull  << 20));  // 32 MB (reuses dead xb)
  unsigned short* hidden = (unsigned short*)(ws + (96ull  << 20));  // 128 MB
  char* meta = ws + (224ull << 20);
  int*   top_e   = (int*)meta;                     // 16384
  float* top_p   = (float*)(meta + (64 << 10));    // 16384
  int*   map     = (int*)(meta + (128 << 10));     // 16384
  float* gate    = (float*)(meta + (192 << 10));   // 16384
  int*   slot_of = (int*)(meta + (256 << 10));     // 16384
  int*   counts  = (int*)(meta + (320 << 10));     // 8
  int*   offsets = counts + 8;
  int*   cursor  = counts + 16;

  // 1. w1 [E][H][F] fp32 -> wT = w1t [E][F][H] bf16  (+ zero 24 meta words)
  transpose_cast_kernel<<<dim3(F_DIM / 64, H_DIM / 64, E_NUM), 256, 0, stream>>>(
      w1, wT, H_DIM, F_DIM, counts);
  // 2. router (+ x -> bf16, + per-block expert counts)
  router_kernel<<<256, 256, 0, stream>>>(x, rw, xb, top_e, top_p, counts);
  // 3. slot assignment (+ offsets publish, + slot_of for combine)
  assign_kernel<<<T_TOKENS / 256, 256, 0, stream>>>(top_e, top_p, counts, cursor,
                                                    map, gate, slot_of, offsets);
  // 4. fc1: hidden = gelu(x @ w1[e]) over routed slots
  moe_gemm_kernel<H_DIM, F_DIM, true>
      <<<dim3(E_NUM, 64, F_DIM / 128), 256, 0, stream>>>(xb, wT, map,
                                                         counts, offsets, hidden);
  // 5. w2 [E][F][H] fp32 -> wT = w2t [E][H][F] bf16 (wT free after fc1)
  transpose_cast_kernel<<<dim3(H_DIM / 64, F_DIM / 64, E_NUM), 256, 0, stream>>>(
      w2, wT, F_DIM, H_DIM, nullptr);
  // 6. fc2: y = gate * (hidden @ w2[e])
  moe_gemm_fc2_kernel<F_DIM, H_DIM>
      <<<dim3(E_NUM, 64, H_DIM / 128), 256, 0, stream>>>(hidden, wT, gate,
                                                         counts, offsets, y);
  // 7. combine two slots per token
  combine_kernel<<<T_TOKENS, 256, 0, stream>>>(y, slot_of, out);
}